// Round 9
// baseline (396.430 us; speedup 1.0000x reference)
//
#include <hip/hip_runtime.h>
#include <math.h>

#define NIMG 8
#define NCLS 80
#define HW 40000
#define M (NCLS*HW)          // 3,200,000 per image
#define UBINS 4096           // uniform bins: bin = (int)(s*4096), monotone in s
#define CANDL 4096
#define SPILL_CAP 65536
#define BCAP 1024
#define CCAP 48              // per-class NMS bucket cap (mean 12.5, 10-sigma safe)
#define TOPK 1000
#define OUTK 100
#define PRE_T 0.05f
#define NMS_T 0.6f
#define FLOOR_BITS 0x3E800000u   // 0.25f
#define FLOOR_SAFE 0.2494f
#define NT1 782              // ceil(M/4096)
#define K1GX 256             // k1 blocks per image (grid-stride over tiles)

// device-global scratch; counters re-zeroed every call, rest guarded by counts
__device__ unsigned int       g_scnt[NIMG][32];    // padded: 128B per image
__device__ unsigned int       g_ovf[NIMG];
__device__ float              g_xthr[NIMG * HW];   // per-pixel spill threshold
__device__ float              g_sct[NIMG * HW];    // exact sigmoid(centerness)
__device__ unsigned long long g_key[NIMG][SPILL_CAP];

__device__ __forceinline__ float sigmoid_exact(float x){
    return 1.0f / (1.0f + expf(-x));   // bit-matches ref (R1-R8: absmax 0)
}

// k0: zero counters; exact sct table; xthr[hw] = logit(FLOOR_SAFE/sct), +inf if >=1.
// Spill rule x >= xthr is a strict superset of {exact score >= 0.25}.
__global__ void k0_init(const float* __restrict__ cent){
    int t = blockIdx.x * blockDim.x + threadIdx.x;
    if (t < NIMG * 32) ((unsigned int*)g_scnt)[t] = 0u;
    if (t < NIMG) g_ovf[t] = 0u;
    if (t < NIMG * HW){
        float pct = sigmoid_exact(cent[t]);
        g_sct[t] = pct;
        float a = FLOOR_SAFE / pct;
        float xt;
        if (a >= 1.0f) xt = 3.0e38f;
        else {
            float am = fminf(a, 0.98f);
            xt = logf(am / (1.0f - am));
        }
        g_xthr[t] = xt;
    }
}

// k1: the ONLY full stream over cls. Grid-stride over tiles (2048 long-lived
// blocks instead of 6256 one-shot blocks): barrier-free inner loop, hot path
// is load+compare only; spill body (expf exact key) is __any-guarded.
__global__ void __launch_bounds__(1024) k1_spill(const float* __restrict__ cls){
    const int n   = blockIdx.y;
    const int tid = threadIdx.x;
    __shared__ unsigned long long skey[BCAP];
    __shared__ unsigned int lcnt, lbase;
    if (tid == 0) lcnt = 0u;
    __syncthreads();
    const float* cls_n = cls + (size_t)n * M;
    const float* thr_n = g_xthr + n * HW;
    const float* sct_n = g_sct  + n * HW;
    for (int tile = blockIdx.x; tile < NT1; tile += K1GX){
        int e0 = tile * 4096 + tid * 4;
        if (e0 < M){                       // M%4==0: full float4 valid
            int c  = e0 / HW;
            int hw = e0 - c * HW;
            float4 x  = *(const float4*)(cls_n + e0);
            float4 th = *(const float4*)(thr_n + hw);
            bool s0 = x.x >= th.x, s1 = x.y >= th.y;
            bool s2 = x.z >= th.z, s3 = x.w >= th.w;
            if (__any(s0 | s1 | s2 | s3)){
                float xs[4] = {x.x, x.y, x.z, x.w};
                bool  ss[4] = {s0, s1, s2, s3};
                #pragma unroll
                for (int j = 0; j < 4; ++j){
                    if (ss[j]){
                        float p = sigmoid_exact(xs[j]);
                        if (p > PRE_T){
                            float s = p * sct_n[hw + j];
                            unsigned long long key =
                                ((unsigned long long)__float_as_uint(s) << 32)
                              | (unsigned long long)(0xFFFFFFFFu -
                                    (unsigned int)((hw + j) * NCLS + c));
                            unsigned int pp = atomicAdd(&lcnt, 1u);
                            if (pp < BCAP) skey[pp] = key;
                        }
                    }
                }
            }
        }
    }
    __syncthreads();
    unsigned int raw = lcnt;
    unsigned int cnt = raw < BCAP ? raw : BCAP;
    if (tid == 0){
        lbase = cnt ? atomicAdd(&g_scnt[n][0], cnt) : 0u;
        if (raw > BCAP) g_ovf[n] = 1u;
    }
    __syncthreads();
    unsigned int base = lbase;
    for (unsigned int i = tid; i < cnt; i += 1024){
        unsigned int pos = base + i;
        if (pos < SPILL_CAP) g_key[n][pos] = skey[i];
    }
}

struct SelPhase {
    unsigned int hist[UBINS];                 // 16 KB
    unsigned int cs[256];                     // 1 KB
    unsigned long long keysL[CANDL];          // 32 KB
};
struct NmsPhase {
    float ox1[TOPK], oy1[TOPK], ox2[TOPK], oy2[TOPK], oar[TOPK];  // 20 KB
    float bxs[TOPK][4];                       // 16 KB
    float sc[TOPK];                           // 4 KB
    unsigned short lab[TOPK];                 // 2 KB
    unsigned char  supp[TOPK];                // 1 KB
    unsigned short bucket[NCLS][CCAP];        // 7.5 KB
    unsigned char  bcnt[NCLS];
    int keeplist[OUTK];
};
union KU { SelPhase sel; NmsPhase nms; };     // ~51 KB

// k2: per image — hist of exact key bits, cut, collect, O(C^2) rank (C~1005),
// then per-class parallel NMS (cross-class IoU provably 0 via the 1e5*label
// offset -> 80 independent greedy chains, no barriers), ballot prefix-scan for
// the first-100 kept, output. Fallbacks: full exact rescan (selection) and
// barrier-loop NMS (bucket overflow).
__global__ void __launch_bounds__(1024) k2_select_nms(const float* __restrict__ cls,
                                                      const float* __restrict__ loc,
                                                      const float* __restrict__ reg,
                                                      const int*   __restrict__ imsz,
                                                      float* __restrict__ out){
    const int n = blockIdx.x;
    const int tid = threadIdx.x;
    const int lane = tid & 63;
    const int wave = tid >> 6;
    __shared__ KU u;
    __shared__ unsigned long long stop[TOPK];
    __shared__ unsigned int wsum[16];
    __shared__ unsigned int lcnt, c025, s_cut, s_flag, s_bovf, s_cnt;

    for (int i = tid; i < UBINS; i += 1024) u.sel.hist[i] = 0u;
    if (tid == 0){ lcnt = 0u; c025 = 0u; s_bovf = 0u; }
    if (tid < TOPK) stop[tid] = 0ull;
    __syncthreads();

    unsigned int scnt_raw = g_scnt[n][0];
    unsigned int S = scnt_raw < SPILL_CAP ? scnt_raw : SPILL_CAP;

    // hist pass (coalesced key reads)
    for (unsigned int i = tid; i < S; i += 1024){
        unsigned long long k = g_key[n][i];
        unsigned int bits = (unsigned int)(k >> 32);
        float s = __uint_as_float(bits);
        atomicAdd(&u.sel.hist[(int)(s * 4096.0f)], 1u);
        unsigned long long mb = __ballot(bits >= FLOOR_BITS);
        if (lane == 0 && mb) atomicAdd(&c025, (unsigned int)__popcll(mb));
    }
    __syncthreads();
    if (tid < 256){
        unsigned int s = 0;
        int base = tid * 16;
        #pragma unroll
        for (int i = 0; i < 16; ++i) s += u.sel.hist[base + i];
        u.sel.cs[tid] = s;
    }
    __syncthreads();
    if (tid == 0){
        unsigned int acc = 0; int cut = 0;
        int c = 255;
        for (; c >= 0; --c){ if (acc + u.sel.cs[c] >= TOPK) break; acc += u.sel.cs[c]; }
        unsigned int Cest = 0;
        if (c >= 0){
            int b = c*16 + 15;
            for (;; --b){
                if (acc + u.sel.hist[b] >= TOPK || b == c*16){ cut = b; break; }
                acc += u.sel.hist[b];
            }
            Cest = acc + u.sel.hist[cut];
        }
        unsigned int fl = (scnt_raw > SPILL_CAP) || g_ovf[n] || (c < 0) ||
                          (c025 < TOPK) || (Cest > CANDL) ? 1u : 0u;
        s_cut = (unsigned int)cut; s_flag = fl;
    }
    __syncthreads();

    if (s_flag){
        // ---- selection fallback: exact full rescan (~never taken)
        for (int i = tid; i < UBINS; i += 1024) u.sel.hist[i] = 0u;
        __syncthreads();
        const float* cls_n = cls + (size_t)n * M;
        const float* sct_n = g_sct + n * HW;
        for (int e = tid; e < M; e += 1024){
            float p = sigmoid_exact(cls_n[e]);
            if (p > PRE_T){
                int c = e / HW; int hw = e - c * HW;
                float s = p * sct_n[hw];
                atomicAdd(&u.sel.hist[(int)(s * 4096.0f)], 1u);
            }
        }
        __syncthreads();
        if (tid < 256){
            unsigned int s = 0;
            int base = tid * 16;
            #pragma unroll
            for (int i = 0; i < 16; ++i) s += u.sel.hist[base + i];
            u.sel.cs[tid] = s;
        }
        __syncthreads();
        if (tid == 0){
            unsigned int acc = 0; int cut = 0; int c = 255;
            for (; c >= 0; --c){ if (acc + u.sel.cs[c] >= TOPK) break; acc += u.sel.cs[c]; }
            if (c >= 0){
                int b = c*16 + 15;
                for (;; --b){ acc += u.sel.hist[b]; if (acc >= TOPK || b == c*16) break; }
                cut = b;
            }
            while (acc > CANDL && cut < UBINS){ acc -= u.sel.hist[cut]; cut++; }
            s_cut = (unsigned int)cut;
        }
        __syncthreads();
        unsigned int cutb = s_cut;
        for (int e = tid; e < M; e += 1024){
            float p = sigmoid_exact(cls_n[e]);
            if (p > PRE_T){
                int c = e / HW; int hw = e - c * HW;
                float s = p * sct_n[hw];
                if ((int)(s * 4096.0f) >= (int)cutb){
                    unsigned int pos = atomicAdd(&lcnt, 1u);
                    if (pos < CANDL){
                        unsigned int idx = (unsigned int)(hw * NCLS + c);
                        u.sel.keysL[pos] = ((unsigned long long)__float_as_uint(s) << 32)
                                         | (unsigned long long)(0xFFFFFFFFu - idx);
                    }
                }
            }
        }
    } else {
        // ---- fast path: collect keys with bin >= cut (ballot-compacted)
        unsigned int cutb = s_cut;
        for (unsigned int i = tid; i < S; i += 1024){
            unsigned long long k = g_key[n][i];
            float s = __uint_as_float((unsigned int)(k >> 32));
            bool pass = ((unsigned int)(int)(s * 4096.0f)) >= cutb;
            unsigned long long mb = __ballot(pass);
            unsigned int wcnt = (unsigned int)__popcll(mb);
            unsigned int base = 0;
            if (lane == 0 && wcnt) base = atomicAdd(&lcnt, wcnt);
            base = (unsigned int)__builtin_amdgcn_readfirstlane((int)base);
            if (pass){
                unsigned int p = base + (unsigned int)__popcll(mb & ((1ull << lane) - 1ull));
                if (p < CANDL) u.sel.keysL[p] = k;
            }
        }
    }
    __syncthreads();

    // exact rank-select top-1000 (unique composite keys -> unique ranks)
    int C = (int)(lcnt < CANDL ? lcnt : CANDL);
    for (int i = tid; i < C; i += 1024){
        unsigned long long k = u.sel.keysL[i];
        int rank = 0;
        for (int j = 0; j < C; ++j) rank += (u.sel.keysL[j] > k) ? 1 : 0;
        if (rank < TOPK) stop[rank] = k;
    }
    __syncthreads();

    // ---- NMS phase (u.nms aliases u.sel)
    float rx1 = 0.f, ry1 = 0.f, rx2 = -1.f, ry2 = -1.f, rar = 1.f;
    float ihh = (float)imsz[2*n + 0];
    float iww = (float)imsz[2*n + 1];
    unsigned long long kk = (tid < TOPK) ? stop[tid] : 0ull;
    __syncthreads();   // stop reads done before union reuse
    if (tid < TOPK){
        unsigned int bits = (unsigned int)(kk >> 32);
        float s = __uint_as_float(bits);
        u.nms.supp[tid] = 0;
        if (s > 0.0f){
            unsigned int idx = 0xFFFFFFFFu - (unsigned int)(kk & 0xFFFFFFFFull);
            int hw = (int)(idx / NCLS);
            int c  = (int)(idx % NCLS);
            int l  = c + 1;
            float x  = loc[2*hw], y = loc[2*hw + 1];
            float r0 = reg[((size_t)n*4 + 0)*HW + hw];
            float r1 = reg[((size_t)n*4 + 1)*HW + hw];
            float r2 = reg[((size_t)n*4 + 2)*HW + hw];
            float r3 = reg[((size_t)n*4 + 3)*HW + hw];
            float x1 = fminf(fmaxf(x - r0, 0.0f), iww - 1.0f);
            float y1 = fminf(fmaxf(y - r1, 0.0f), ihh - 1.0f);
            float x2 = fminf(fmaxf(x + r2, 0.0f), iww - 1.0f);
            float y2 = fminf(fmaxf(y + r3, 0.0f), ihh - 1.0f);
            u.nms.bxs[tid][0] = x1; u.nms.bxs[tid][1] = y1;
            u.nms.bxs[tid][2] = x2; u.nms.bxs[tid][3] = y2;
            float off = (float)l * 100000.0f;   // fp32, as reference (quantizes!)
            float a1 = x1 + off, b1 = y1 + off, a2 = x2 + off, b2 = y2 + off;
            float ar = (a2 - a1 + 1.0f) * (b2 - b1 + 1.0f);
            u.nms.ox1[tid] = a1; u.nms.oy1[tid] = b1;
            u.nms.ox2[tid] = a2; u.nms.oy2[tid] = b2; u.nms.oar[tid] = ar;
            rx1 = a1; ry1 = b1; rx2 = a2; ry2 = b2; rar = ar;
            u.nms.sc[tid] = s; u.nms.lab[tid] = (unsigned short)l;
        } else {
            u.nms.sc[tid] = 0.0f; u.nms.lab[tid] = 0;
            u.nms.bxs[tid][0] = u.nms.bxs[tid][1] = 0.0f;
            u.nms.bxs[tid][2] = u.nms.bxs[tid][3] = 0.0f;
            u.nms.ox1[tid] = 0.f; u.nms.oy1[tid] = 0.f;
            u.nms.ox2[tid] = -1.f; u.nms.oy2[tid] = -1.f; u.nms.oar[tid] = 1.f;
        }
    }
    __syncthreads();

    // per-class grouping (thread = class): members in rank order
    if (tid < NCLS){
        int cnt = 0;
        for (int i = 0; i < TOPK; ++i){
            if (u.nms.lab[i] == (unsigned short)(tid + 1) && u.nms.sc[i] > 0.0f){
                if (cnt < CCAP) u.nms.bucket[tid][cnt] = (unsigned short)i;
                cnt++;
            }
        }
        u.nms.bcnt[tid] = (unsigned char)(cnt < CCAP ? cnt : CCAP);
        if (cnt > CCAP) atomicOr(&s_bovf, 1u);
    }
    __syncthreads();

    if (!s_bovf){
        // 80 independent greedy chains, barrier-free
        if (tid < NCLS){
            int kc = u.nms.bcnt[tid];
            for (int a = 0; a < kc; ++a){
                int ia = u.nms.bucket[tid][a];
                if (u.nms.supp[ia]) continue;          // ia kept
                float ax1 = u.nms.ox1[ia], ay1 = u.nms.oy1[ia];
                float ax2 = u.nms.ox2[ia], ay2 = u.nms.oy2[ia], aar = u.nms.oar[ia];
                for (int b = a + 1; b < kc; ++b){
                    int ib = u.nms.bucket[tid][b];
                    if (u.nms.supp[ib]) continue;
                    float ix1 = fmaxf(ax1, u.nms.ox1[ib]);
                    float iy1 = fmaxf(ay1, u.nms.oy1[ib]);
                    float ix2 = fminf(ax2, u.nms.ox2[ib]);
                    float iy2 = fminf(ay2, u.nms.oy2[ib]);
                    float iw_ = fmaxf(ix2 - ix1 + 1.0f, 0.0f);
                    float ih_ = fmaxf(iy2 - iy1 + 1.0f, 0.0f);
                    float inter = iw_ * ih_;
                    float iou = inter / (aar + u.nms.oar[ib] - inter);
                    if (iou > NMS_T) u.nms.supp[ib] = 1;
                }
            }
        }
        __syncthreads();
        // ballot prefix-scan: first 100 kept in rank order
        bool kp = (tid < TOPK) && (u.nms.sc[tid] > 0.0f) && !u.nms.supp[tid];
        unsigned long long mb = __ballot(kp);
        if (lane == 0) wsum[wave] = (unsigned int)__popcll(mb);
        __syncthreads();
        unsigned int pre = 0, tot = 0;
        for (int w = 0; w < 16; ++w){
            unsigned int v = wsum[w];
            if (w < wave) pre += v;
            tot += v;
        }
        pre += (unsigned int)__popcll(mb & ((1ull << lane) - 1ull));
        if (kp && pre < OUTK) u.nms.keeplist[pre] = tid;
        if (tid == 0) s_cnt = tot < OUTK ? tot : OUTK;
    } else {
        // bucket-overflow fallback: R8's barrier-loop greedy (proven)
        int cnt = 0;
        for (int i = 0; i < TOPK; ++i){
            bool keep_i = (u.nms.sc[i] > 0.0f) && !u.nms.supp[i];
            if (keep_i){
                if (tid == 0) u.nms.keeplist[cnt] = i;
                if (tid < TOPK && tid != i){
                    float ix1 = fmaxf(u.nms.ox1[i], rx1);
                    float iy1 = fmaxf(u.nms.oy1[i], ry1);
                    float ix2 = fminf(u.nms.ox2[i], rx2);
                    float iy2 = fminf(u.nms.oy2[i], ry2);
                    float iw_ = fmaxf(ix2 - ix1 + 1.0f, 0.0f);
                    float ih_ = fmaxf(iy2 - iy1 + 1.0f, 0.0f);
                    float inter = iw_ * ih_;
                    float iou = inter / (u.nms.oar[i] + rar - inter);
                    if (iou > NMS_T) u.nms.supp[tid] = 1;
                }
                cnt++;
                __syncthreads();
                if (cnt == OUTK) break;
            }
        }
        if (tid == 0) s_cnt = cnt;
    }
    __syncthreads();

    if (tid < OUTK){
        float r0=0.f,r1=0.f,r2=0.f,r3=0.f,r4=0.f,r5=0.f;
        if (tid < (int)s_cnt){
            int i = u.nms.keeplist[tid];
            r0 = u.nms.bxs[i][0]; r1 = u.nms.bxs[i][1];
            r2 = u.nms.bxs[i][2]; r3 = u.nms.bxs[i][3];
            r4 = sqrtf(u.nms.sc[i]); r5 = (float)u.nms.lab[i];
        }
        float* o = out + ((size_t)n*OUTK + tid)*6;
        o[0]=r0; o[1]=r1; o[2]=r2; o[3]=r3; o[4]=r4; o[5]=r5;
    }
}

extern "C" void kernel_launch(void* const* d_in, const int* in_sizes, int n_in,
                              void* d_out, int out_size, void* d_ws, size_t ws_size,
                              hipStream_t stream){
    const float* loc  = (const float*)d_in[0];
    const float* cls  = (const float*)d_in[1];
    const float* reg  = (const float*)d_in[2];
    const float* cent = (const float*)d_in[3];
    const int*   imsz = (const int*)d_in[4];
    float* out = (float*)d_out;

    hipLaunchKernelGGL(k0_init,       dim3(625),        dim3(512),  0, stream, cent);
    hipLaunchKernelGGL(k1_spill,      dim3(K1GX, NIMG), dim3(1024), 0, stream, cls);
    hipLaunchKernelGGL(k2_select_nms, dim3(NIMG),       dim3(1024), 0, stream,
                       cls, loc, reg, imsz, out);
}